// Round 16
// baseline (237.527 us; speedup 1.0000x reference)
//
#include <hip/hip_runtime.h>

#define BSZ 8
#define TLEN 1024
#define DM 64
#define DI 128
#define DS 32
#define NCHUNK 16
#define CLEN 64
#define GEXT 1028   // 1024 z-tokens + up to 4 appended pred tokens (global token axis)

__device__ __forceinline__ float siluf(float x) { return x / (1.f + expf(-x)); }
__device__ __forceinline__ float softplusf(float x) { return (x > 20.f) ? x : log1pf(expf(x)); }

// ---------------- fused encoder + reconstruction decoder: 16 tokens/block, 512 blocks ----------------
__global__ __launch_bounds__(256) void enc_xrec_kernel(
    const float* __restrict__ x,
    const float* __restrict__ We1, const float* __restrict__ be1,
    const float* __restrict__ We2, const float* __restrict__ be2,
    const float* __restrict__ Wd1, const float* __restrict__ bd1,
    const float* __restrict__ Wd2, const float* __restrict__ bd2,
    float* __restrict__ z, float* __restrict__ x_rec)
{
  __shared__ float s_x[16*32];
  __shared__ float s_h1[16*64];
  __shared__ float s_z[16*64];
  __shared__ float s_h2[16*64];
  const int tid = threadIdx.x;
  const int t0 = blockIdx.x * 16;
  s_x[tid]       = x[(size_t)t0*32 + tid];
  s_x[tid + 256] = x[(size_t)t0*32 + tid + 256];
  __syncthreads();
  const int j = tid & 63, tg = tid >> 6;
  {
    float w[32];
    #pragma unroll
    for (int k = 0; k < 32; k++) w[k] = We1[k*64 + j];
    #pragma unroll
    for (int q = 0; q < 4; q++) {
      int t = tg*4 + q;
      float a = be1[j];
      #pragma unroll
      for (int k = 0; k < 32; k++) a = fmaf(s_x[t*32 + k], w[k], a);
      s_h1[t*64 + j] = fmaxf(a, 0.f);
    }
  }
  __syncthreads();
  {
    float w[64];
    #pragma unroll
    for (int k = 0; k < 64; k++) w[k] = We2[k*64 + j];
    #pragma unroll
    for (int q = 0; q < 4; q++) {
      int t = tg*4 + q;
      float a = be2[j];
      #pragma unroll
      for (int k = 0; k < 64; k++) a = fmaf(s_h1[t*64 + k], w[k], a);
      s_z[t*64 + j] = a;
      z[(size_t)(t0 + t)*64 + j] = a;
    }
  }
  __syncthreads();
  {
    float w[64];
    #pragma unroll
    for (int k = 0; k < 64; k++) w[k] = Wd1[k*64 + j];
    #pragma unroll
    for (int q = 0; q < 4; q++) {
      int t = tg*4 + q;
      float a = bd1[j];
      #pragma unroll
      for (int k = 0; k < 64; k++) a = fmaf(s_z[t*64 + k], w[k], a);
      s_h2[t*64 + j] = fmaxf(a, 0.f);
    }
  }
  __syncthreads();
  {
    const int c = tid & 31, tg2 = tid >> 5;
    float w[64];
    #pragma unroll
    for (int k = 0; k < 64; k++) w[k] = Wd2[k*32 + c];
    #pragma unroll
    for (int q = 0; q < 2; q++) {
      int t = tg2*2 + q;
      float a = bd2[c];
      #pragma unroll
      for (int k = 0; k < 64; k++) a = fmaf(s_h2[t*64 + k], w[k], a);
      x_rec[(size_t)(t0 + t)*32 + c] = a;
    }
  }
}

// ---------------- pre: 8 tokens/block (+3 halo), 1024 blocks ----------------
// (256,4): VGPR hard cap 128 -> 4 blocks/CU guaranteed. The 11 halo rows are
// CONTIGUOUS (consecutive tokens x DM), so one base pointer + immediate offsets;
// freed VGPRs spent on an explicit 1-iteration register double-buffer of rows+weights.
__global__ __launch_bounds__(256,4) void pre_kernel(
    const float* __restrict__ in, int in_stride,
    const float* __restrict__ Win, const float* __restrict__ Wconv, const float* __restrict__ bconv,
    const float* __restrict__ Wxproj, const float* __restrict__ Wdt, const float* __restrict__ bdt,
    float* __restrict__ xibuf, float* __restrict__ resgbuf,
    float2* __restrict__ ddbuf, float* __restrict__ Bbuf, float* __restrict__ Cbuf,
    float* __restrict__ xzout)
{
  __shared__ float s_xi[8*128];
  __shared__ float s_dtr[8*4];
  const int tid = threadIdx.x;
  const int b  = blockIdx.x >> 7;
  const int t0 = (blockIdx.x & 127) * 8;

  float acc[11];
  #pragma unroll
  for (int r = 0; r < 11; r++) acc[r] = 0.f;

  if (t0 > 0) {
    const float* base = in + ((size_t)b*in_stride + t0 - 3)*DM;
    float4 xv[11];
    #pragma unroll
    for (int r = 0; r < 11; r++) xv[r] = *(const float4*)(base + r*DM);
    float w0 = Win[0*256 + tid], w1 = Win[1*256 + tid],
          w2 = Win[2*256 + tid], w3 = Win[3*256 + tid];
    #pragma unroll
    for (int k4 = 0; k4 < 16; k4++) {
      float4 nxt[11];
      float nw0 = 0.f, nw1 = 0.f, nw2 = 0.f, nw3 = 0.f;
      if (k4 < 15) {
        #pragma unroll
        for (int r = 0; r < 11; r++) nxt[r] = *(const float4*)(base + r*DM + (k4+1)*4);
        nw0 = Win[((k4+1)*4+0)*256 + tid];
        nw1 = Win[((k4+1)*4+1)*256 + tid];
        nw2 = Win[((k4+1)*4+2)*256 + tid];
        nw3 = Win[((k4+1)*4+3)*256 + tid];
      }
      #pragma unroll
      for (int r = 0; r < 11; r++) {
        acc[r] = fmaf(xv[r].x, w0, acc[r]);
        acc[r] = fmaf(xv[r].y, w1, acc[r]);
        acc[r] = fmaf(xv[r].z, w2, acc[r]);
        acc[r] = fmaf(xv[r].w, w3, acc[r]);
      }
      if (k4 < 15) {
        #pragma unroll
        for (int r = 0; r < 11; r++) xv[r] = nxt[r];
        w0 = nw0; w1 = nw1; w2 = nw2; w3 = nw3;
      }
    }
  } else {
    // first tile: rows 0..2 are zero-padding; tokens 0..7 = rows 3..10
    const float* base = in + (size_t)b*in_stride*DM;
    #pragma unroll
    for (int k4 = 0; k4 < 16; k4++) {
      float w0 = Win[(k4*4+0)*256 + tid];
      float w1 = Win[(k4*4+1)*256 + tid];
      float w2 = Win[(k4*4+2)*256 + tid];
      float w3 = Win[(k4*4+3)*256 + tid];
      #pragma unroll
      for (int r = 3; r < 11; r++) {
        float4 xv = *(const float4*)(base + (r-3)*DM + k4*4);
        acc[r] = fmaf(xv.x, w0, acc[r]);
        acc[r] = fmaf(xv.y, w1, acc[r]);
        acc[r] = fmaf(xv.z, w2, acc[r]);
        acc[r] = fmaf(xv.w, w3, acc[r]);
      }
    }
  }

  if (tid < 128) {
    float4 wc = *(const float4*)&Wconv[tid*4];
    float bc = bconv[tid];
    const bool store_xz = (t0 == TLEN-8);   // only ext_all's conv (tokens >=1021) reads xz
    #pragma unroll
    for (int tau = 0; tau < 8; tau++) {
      float v = bc;
      v = fmaf(acc[tau+0], wc.x, v);
      v = fmaf(acc[tau+1], wc.y, v);
      v = fmaf(acc[tau+2], wc.z, v);
      v = fmaf(acc[tau+3], wc.w, v);
      float xiv = siluf(v);
      s_xi[tau*128 + tid] = xiv;
      xibuf[((size_t)b*TLEN + t0 + tau)*DI + tid] = xiv;
      if (store_xz) xzout[((size_t)b*GEXT + t0 + tau)*128 + tid] = acc[tau+3];
    }
  } else {
    int d = tid - 128;
    #pragma unroll
    for (int tau = 0; tau < 8; tau++)
      resgbuf[((size_t)b*TLEN + t0 + tau)*DI + d] = siluf(acc[tau+3]);
  }
  __syncthreads();
  {
    const int wv = tid >> 6, c = tid & 63;
    float a0 = 0.f, a1 = 0.f;
    const float4* x0 = (const float4*)&s_xi[(wv*2+0)*128];
    const float4* x1 = (const float4*)&s_xi[(wv*2+1)*128];
    #pragma unroll 4
    for (int k4 = 0; k4 < 32; k4++) {
      float wq0 = Wxproj[(k4*4+0)*68 + 4 + c];
      float wq1 = Wxproj[(k4*4+1)*68 + 4 + c];
      float wq2 = Wxproj[(k4*4+2)*68 + 4 + c];
      float wq3 = Wxproj[(k4*4+3)*68 + 4 + c];
      float4 v0 = x0[k4], v1 = x1[k4];
      a0 = fmaf(v0.x,wq0, fmaf(v0.y,wq1, fmaf(v0.z,wq2, fmaf(v0.w,wq3, a0))));
      a1 = fmaf(v1.x,wq0, fmaf(v1.y,wq1, fmaf(v1.z,wq2, fmaf(v1.w,wq3, a1))));
    }
    size_t tb = (size_t)b*TLEN + t0 + wv*2;
    if (c < 32) {
      Bbuf[(tb+0)*DS + c] = a0; Bbuf[(tb+1)*DS + c] = a1;
    } else {
      int cc = c - 32;
      Cbuf[(tb+0)*DS + cc] = a0; Cbuf[(tb+1)*DS + cc] = a1;
    }
  }
  if (tid < 32) {
    int tau = tid >> 2, cc = tid & 3;
    float a = 0.f;
    const float4* xx = (const float4*)&s_xi[tau*128];
    #pragma unroll 4
    for (int k4 = 0; k4 < 32; k4++) {
      float4 v = xx[k4];
      a = fmaf(v.x, Wxproj[(k4*4+0)*68 + cc], a);
      a = fmaf(v.y, Wxproj[(k4*4+1)*68 + cc], a);
      a = fmaf(v.z, Wxproj[(k4*4+2)*68 + cc], a);
      a = fmaf(v.w, Wxproj[(k4*4+3)*68 + cc], a);
    }
    s_dtr[tau*4 + cc] = a;
  }
  __syncthreads();
  #pragma unroll
  for (int u = 0; u < 4; u++) {
    int i = tid + u*256;
    int tau = i >> 7, d = i & 127;
    float a = bdt[d];
    #pragma unroll
    for (int r = 0; r < 4; r++) a = fmaf(s_dtr[tau*4 + r], Wdt[r*128 + d], a);
    float dtv = softplusf(a);
    ddbuf[((size_t)b*TLEN + t0 + tau)*DI + d] = make_float2(dtv, dtv * s_xi[i]);
  }
}

// B/C chunk swizzle (r4): breaks the stride-68 8-way conflict down to <=2-way.
#define BSWZ(row3) (((row3)&3)<<1)

// XCD work swizzle (r9): consecutive work-ids share blockIdx%8 -> co-XCD L2 reuse.
__device__ __forceinline__ int xcd_wid_4096() {
  return (blockIdx.x >> 3) | ((blockIdx.x & 7) << 9);
}

// ---------------- scan phase 1: per-chunk local scan from h=0; emits (h_end, decay) ----------------
__global__ __launch_bounds__(128) void scan1_kernel(
    const float2* __restrict__ ddbuf, const float* __restrict__ Bbuf,
    const float* __restrict__ Alog, float2* __restrict__ hc)
{
  __shared__ float2 s_dd[4][CLEN];
  __shared__ float  s_Bt[32][68];
  const int tid = threadIdx.x;
  const int ch = tid >> 5, s = tid & 31;
  const int wid = xcd_wid_4096();
  const int dg = wid & 31;
  const int c  = (wid >> 5) & 15;
  const int b  = wid >> 9;
  const int d0 = dg * 4;
  const float A = -__expf(Alog[(d0 + ch)*DS + s]);
  const float2* ddg = ddbuf + ((size_t)b*TLEN + c*CLEN)*DI + d0;
  const float*  Bg  = Bbuf  + ((size_t)b*TLEN + c*CLEN)*DS;
  {
    int t = tid >> 1, half = tid & 1;
    float4 rdd = *(const float4*)((const float*)(ddg + (size_t)t*DI) + half*4);
    s_dd[2*half+0][t] = make_float2(rdd.x, rdd.y);
    s_dd[2*half+1][t] = make_float2(rdd.z, rdd.w);
    #pragma unroll
    for (int j = 0; j < 4; j++) {
      int q = tid + 128*j; int tt = q >> 3, k4 = q & 7;
      float4 rB = *(const float4*)(Bg + tt*DS + k4*4);
      int cp = (((tt>>2) ^ BSWZ(k4>>1)) << 2) + (tt & 3);
      s_Bt[k4*4+0][cp] = rB.x; s_Bt[k4*4+1][cp] = rB.y;
      s_Bt[k4*4+2][cp] = rB.z; s_Bt[k4*4+3][cp] = rB.w;
    }
  }
  __syncthreads();
  float h = 0.f, dts = 0.f;
  const float4* dd4 = (const float4*)&s_dd[ch][0];
  const float4* bt4 = (const float4*)&s_Bt[s][0];
  const int swr = BSWZ(s>>3);
  #pragma unroll
  for (int j = 0; j < 8; j++) {
    float4 e0 = dd4[4*j+0], e1 = dd4[4*j+1], e2 = dd4[4*j+2], e3 = dd4[4*j+3];
    float4 bb0 = bt4[(2*j)^swr], bb1 = bt4[(2*j+1)^swr];
    h = fmaf(__expf(e0.x*A), h, e0.y*bb0.x);
    h = fmaf(__expf(e0.z*A), h, e0.w*bb0.y);
    h = fmaf(__expf(e1.x*A), h, e1.y*bb0.z);
    h = fmaf(__expf(e1.z*A), h, e1.w*bb0.w);
    h = fmaf(__expf(e2.x*A), h, e2.y*bb1.x);
    h = fmaf(__expf(e2.z*A), h, e2.w*bb1.y);
    h = fmaf(__expf(e3.x*A), h, e3.y*bb1.z);
    h = fmaf(__expf(e3.z*A), h, e3.w*bb1.w);
    dts += (e0.x + e0.z) + (e1.x + e1.z) + (e2.x + e2.z) + (e3.x + e3.z);
  }
  int o = ((b*NCHUNK + c)*DI + d0 + ch)*DS + s;
  hc[o] = make_float2(h, __expf(A*dts));
}

// ---------------- scan phase 3: prefix-combine + rescan chunk, emit y + h(1023) ----------------
__global__ __launch_bounds__(128) void scan3_kernel(
    const float2* __restrict__ ddbuf, const float* __restrict__ Bbuf, const float* __restrict__ Cbuf,
    const float* __restrict__ Alog, const float2* __restrict__ hc, float* __restrict__ ysbuf,
    float* __restrict__ hout)
{
  __shared__ float2 s_dd[4][CLEN];
  __shared__ float  s_Bt[32][68];
  __shared__ float  s_Ct[32][68];
  __shared__ float  s_p[128][33];
  const int tid = threadIdx.x;
  const int ch = tid >> 5, s = tid & 31;
  const int wid = xcd_wid_4096();
  const int dg = wid & 31;
  const int c  = (wid >> 5) & 15;
  const int b  = wid >> 9;
  const int d0 = dg * 4;
  const float A = -__expf(Alog[(d0 + ch)*DS + s]);
  const float2* ddg = ddbuf + ((size_t)b*TLEN + c*CLEN)*DI + d0;
  const float*  Bg  = Bbuf  + ((size_t)b*TLEN + c*CLEN)*DS;
  const float*  Cg  = Cbuf  + ((size_t)b*TLEN + c*CLEN)*DS;

  const int ob = (d0 + ch)*DS + s;
  float2 v[15];
  #pragma unroll
  for (int q = 0; q < 15; q++) v[q] = hc[(size_t)(b*NCHUNK + q)*4096 + ob];

  {
    int t = tid >> 1, half = tid & 1;
    float4 rdd = *(const float4*)((const float*)(ddg + (size_t)t*DI) + half*4);
    s_dd[2*half+0][t] = make_float2(rdd.x, rdd.y);
    s_dd[2*half+1][t] = make_float2(rdd.z, rdd.w);
    #pragma unroll
    for (int j = 0; j < 4; j++) {
      int q = tid + 128*j; int tt = q >> 3, k4 = q & 7;
      float4 rB = *(const float4*)(Bg + tt*DS + k4*4);
      float4 rC = *(const float4*)(Cg + tt*DS + k4*4);
      int cp = (((tt>>2) ^ BSWZ(k4>>1)) << 2) + (tt & 3);
      s_Bt[k4*4+0][cp] = rB.x; s_Bt[k4*4+1][cp] = rB.y;
      s_Bt[k4*4+2][cp] = rB.z; s_Bt[k4*4+3][cp] = rB.w;
      s_Ct[k4*4+0][cp] = rC.x; s_Ct[k4*4+1][cp] = rC.y;
      s_Ct[k4*4+2][cp] = rC.z; s_Ct[k4*4+3][cp] = rC.w;
    }
  }
  float h = 0.f;
  #pragma unroll
  for (int q = 0; q < 15; q++)
    if (q < c) h = fmaf(v[q].y, h, v[q].x);
  __syncthreads();

  const float4* dd4 = (const float4*)&s_dd[ch][0];
  const float4* bt4 = (const float4*)&s_Bt[s][0];
  const float4* ct4 = (const float4*)&s_Ct[s][0];
  const int swr = BSWZ(s>>3);
  float* pr = &s_p[tid][0];
  #pragma unroll
  for (int half = 0; half < 2; half++) {
    #pragma unroll
    for (int j = 0; j < 4; j++) {
      const int jj = half*4 + j;
      float4 e0 = dd4[4*jj+0], e1 = dd4[4*jj+1], e2 = dd4[4*jj+2], e3 = dd4[4*jj+3];
      float4 bb0 = bt4[(2*jj)^swr], bb1 = bt4[(2*jj+1)^swr];
      float4 cc0 = ct4[(2*jj)^swr], cc1 = ct4[(2*jj+1)^swr];
      h = fmaf(__expf(e0.x*A), h, e0.y*bb0.x); pr[8*j+0] = h*cc0.x;
      h = fmaf(__expf(e0.z*A), h, e0.w*bb0.y); pr[8*j+1] = h*cc0.y;
      h = fmaf(__expf(e1.x*A), h, e1.y*bb0.z); pr[8*j+2] = h*cc0.z;
      h = fmaf(__expf(e1.z*A), h, e1.w*bb0.w); pr[8*j+3] = h*cc0.w;
      h = fmaf(__expf(e2.x*A), h, e2.y*bb1.x); pr[8*j+4] = h*cc1.x;
      h = fmaf(__expf(e2.z*A), h, e2.w*bb1.y); pr[8*j+5] = h*cc1.y;
      h = fmaf(__expf(e3.x*A), h, e3.y*bb1.z); pr[8*j+6] = h*cc1.z;
      h = fmaf(__expf(e3.z*A), h, e3.w*bb1.w); pr[8*j+7] = h*cc1.w;
    }
    __syncthreads();
    {
      const int ch2 = tid & 3;
      const int tq  = tid >> 2;
      float a = 0.f;
      #pragma unroll
      for (int s2 = 0; s2 < 32; s2++) a += s_p[ch2*32 + s2][tq];
      ysbuf[(size_t)(b*TLEN + c*CLEN + half*32 + tq)*DI + d0 + ch2] = a;
    }
    __syncthreads();
  }
  if (c == 15) hout[(size_t)(b*DI + d0 + ch)*DS + s] = h;
}

// ---------------- post: 8 tokens/block, 1024 blocks ----------------
__global__ __launch_bounds__(256,4) void post_kernel(
    const float* __restrict__ ysbuf, const float* __restrict__ xibuf, const float* __restrict__ resgbuf,
    const float* __restrict__ Dp, const float* __restrict__ Wout,
    const float* __restrict__ basebuf, int base_stride,
    float* __restrict__ curg, float* __restrict__ zdyn, float* __restrict__ predz,
    const float* __restrict__ gamma, const float* __restrict__ beta,
    const float* __restrict__ Wd1, const float* __restrict__ bd1,
    const float* __restrict__ Wd2, const float* __restrict__ bd2,
    float* __restrict__ xdyn, int mode)
{
  __shared__ float s_y[8*128];
  __shared__ float s_z[8*64];
  __shared__ float s_h[8*64];
  const int tid = threadIdx.x;
  const int b  = blockIdx.x >> 7;
  const int t0 = (blockIdx.x & 127) * 8;
  #pragma unroll
  for (int u = 0; u < 4; u++) {
    int i = tid + u*256;
    size_t g = (size_t)(b*TLEN + t0)*DI + i;
    s_y[i] = (ysbuf[g] + xibuf[g]*Dp[i & 127]) * resgbuf[g];
  }
  __syncthreads();
  #pragma unroll
  for (int u = 0; u < 2; u++) {
    int i = tid + u*256;
    int tau = i >> 6, c = i & 63;
    float a = 0.f;
    const float4* yy = (const float4*)&s_y[tau*128];
    #pragma unroll 4
    for (int k4 = 0; k4 < 32; k4++) {
      float4 vv = yy[k4];
      a = fmaf(vv.x, Wout[(k4*4+0)*64 + c], a);
      a = fmaf(vv.y, Wout[(k4*4+1)*64 + c], a);
      a = fmaf(vv.z, Wout[(k4*4+2)*64 + c], a);
      a = fmaf(vv.w, Wout[(k4*4+3)*64 + c], a);
    }
    float base = basebuf[((size_t)b*base_stride + t0 + tau)*DM + c];
    float val = base + a;
    if (mode == 0) {
      curg[((size_t)b*GEXT + t0 + tau)*DM + c] = val;
    } else {
      float sum = val;
      #pragma unroll
      for (int m = 1; m < 64; m <<= 1) sum += __shfl_xor(sum, m);
      float mean = sum * (1.f/64.f);
      float dv = val - mean;
      float vs = dv*dv;
      #pragma unroll
      for (int m = 1; m < 64; m <<= 1) vs += __shfl_xor(vs, m);
      float oln = dv * rsqrtf(vs*(1.f/64.f) + 1e-5f) * gamma[c] + beta[c];
      zdyn[(size_t)(b*TLEN + t0 + tau)*DM + c] = oln;
      s_z[tau*64 + c] = oln;
      if (t0 + tau == TLEN-1) predz[(size_t)(b*4 + 0)*DM + c] = oln;
    }
  }
  if (mode == 1) {
    __syncthreads();
    #pragma unroll
    for (int u = 0; u < 2; u++) {
      int i = tid + u*256;
      int t = i >> 6, j = i & 63;
      float a = bd1[j];
      const float4* zz = (const float4*)&s_z[t*64];
      #pragma unroll 4
      for (int k4 = 0; k4 < 16; k4++) {
        float4 zv = zz[k4];
        a = fmaf(zv.x, Wd1[(k4*4+0)*64 + j], a);
        a = fmaf(zv.y, Wd1[(k4*4+1)*64 + j], a);
        a = fmaf(zv.z, Wd1[(k4*4+2)*64 + j], a);
        a = fmaf(zv.w, Wd1[(k4*4+3)*64 + j], a);
      }
      s_h[i] = fmaxf(a, 0.f);
    }
    __syncthreads();
    {
      int t = tid >> 5, c = tid & 31;
      float a = bd2[c];
      const float4* hh = (const float4*)&s_h[t*64];
      #pragma unroll 4
      for (int k4 = 0; k4 < 16; k4++) {
        float4 hv = hh[k4];
        a = fmaf(hv.x, Wd2[(k4*4+0)*32 + c], a);
        a = fmaf(hv.y, Wd2[(k4*4+1)*32 + c], a);
        a = fmaf(hv.z, Wd2[(k4*4+2)*32 + c], a);
        a = fmaf(hv.w, Wd2[(k4*4+3)*32 + c], a);
      }
      xdyn[(size_t)(b*TLEN + t0 + t)*32 + c] = a;
    }
  }
}

// ---------------- one-token mamba step (shared helper for ext_all) ----------------
__device__ __forceinline__ void mamba_token(
    int tid, int b, int gn, const float* __restrict__ s_in,
    float* __restrict__ xzg, float* __restrict__ hbuf,
    const float* __restrict__ Win, const float* __restrict__ Wcv, const float* __restrict__ bcv,
    const float* __restrict__ Wxp, const float* __restrict__ Wdt, const float* __restrict__ bdt,
    const float* __restrict__ Al, const float* __restrict__ Dpp, const float* __restrict__ Wo,
    float* __restrict__ s_xz, float* __restrict__ s_xi, float* __restrict__ s_rg,
    float* __restrict__ s_dt, float* __restrict__ s_B, float* __restrict__ s_C,
    float* __restrict__ s_dtr, float* __restrict__ s_yp, float* __restrict__ s_y,
    float* __restrict__ s_ssm)
{
  {
    float a = 0.f;
    #pragma unroll
    for (int k = 0; k < 64; k++) a = fmaf(s_in[k], Win[k*256 + tid], a);
    s_xz[tid] = a;
  }
  __syncthreads();
  if (tid < 128) {
    xzg[((size_t)b*GEXT + gn)*128 + tid] = s_xz[tid];
    float acc = bcv[tid];
    acc = fmaf(xzg[((size_t)b*GEXT + gn-3)*128 + tid], Wcv[tid*4+0], acc);
    acc = fmaf(xzg[((size_t)b*GEXT + gn-2)*128 + tid], Wcv[tid*4+1], acc);
    acc = fmaf(xzg[((size_t)b*GEXT + gn-1)*128 + tid], Wcv[tid*4+2], acc);
    acc = fmaf(s_xz[tid], Wcv[tid*4+3], acc);
    s_xi[tid] = siluf(acc);
    s_rg[tid] = siluf(s_xz[128 + tid]);
  }
  __syncthreads();
  if (tid < 68) {
    float a = 0.f;
    #pragma unroll 4
    for (int k = 0; k < 128; k++) a = fmaf(s_xi[k], Wxp[k*68 + tid], a);
    if (tid < 4)       s_dtr[tid] = a;
    else if (tid < 36) s_B[tid-4] = a;
    else               s_C[tid-36] = a;
  }
  __syncthreads();
  if (tid < 128) {
    float a = bdt[tid];
    #pragma unroll
    for (int r = 0; r < 4; r++) a = fmaf(s_dtr[r], Wdt[r*128 + tid], a);
    s_dt[tid] = softplusf(a);
  }
  __syncthreads();
  {
    int d = tid >> 1, sh = (tid & 1) * 16;
    float dtd = s_dt[d], dtxd = dtd * s_xi[d];
    float yp = 0.f;
    #pragma unroll
    for (int q = 0; q < 16; q++) {
      int s = sh + q;
      size_t oo = (size_t)(b*DI + d)*DS + s;
      float A = -__expf(Al[d*DS + s]);
      float h = hbuf[oo];
      h = fmaf(__expf(dtd*A), h, dtxd*s_B[s]);
      hbuf[oo] = h;
      yp = fmaf(s_C[s], h, yp);
    }
    s_yp[(tid & 1)*128 + d] = yp;
  }
  __syncthreads();
  if (tid < 128) s_y[tid] = ((s_yp[tid] + s_yp[128 + tid]) + s_xi[tid]*Dpp[tid]) * s_rg[tid];
  __syncthreads();
  if (tid < 64) {
    float a = 0.f;
    #pragma unroll 4
    for (int k = 0; k < 128; k++) a = fmaf(s_y[k], Wo[k*64 + tid], a);
    s_ssm[tid] = a;
  }
  __syncthreads();
}

// ---------------- ext_all: passes 1..3 in ONE 8-block kernel + fused x_pred decoder ----------------
__global__ __launch_bounds__(256) void ext_all_kernel(
    float* __restrict__ predz,
    float* __restrict__ xz0, float* __restrict__ xz1,
    float* __restrict__ hbuf0, float* __restrict__ hbuf1,
    const float* __restrict__ Win0, const float* __restrict__ Wcv0, const float* __restrict__ bcv0,
    const float* __restrict__ Wxp0, const float* __restrict__ Wdt0, const float* __restrict__ bdt0,
    const float* __restrict__ Al0, const float* __restrict__ Dp0, const float* __restrict__ Wo0,
    const float* __restrict__ Win1, const float* __restrict__ Wcv1, const float* __restrict__ bcv1,
    const float* __restrict__ Wxp1, const float* __restrict__ Wdt1, const float* __restrict__ bdt1,
    const float* __restrict__ Al1, const float* __restrict__ Dp1, const float* __restrict__ Wo1,
    const float* __restrict__ gamma, const float* __restrict__ beta,
    const float* __restrict__ Wd1, const float* __restrict__ bd1,
    const float* __restrict__ Wd2, const float* __restrict__ bd2,
    float* __restrict__ x_pred)
{
  __shared__ float s_in[64], s_cg[64], s_ssm[64];
  __shared__ float s_xz[256], s_yp[256];
  __shared__ float s_xi[128], s_rg[128], s_dt[128], s_y[128];
  __shared__ float s_B[32], s_C[32], s_dtr[4];
  __shared__ float s_pz[4][64];
  __shared__ float s_h[4][64];
  const int tid = threadIdx.x;
  const int b = blockIdx.x;

  if (tid < 64) s_pz[0][tid] = predz[(size_t)(b*4 + 0)*DM + tid];
  __syncthreads();

  for (int p = 1; p <= 3; p++) {
    const int gn = 1023 + p;
    if (tid < 64) s_in[tid] = s_pz[p-1][tid];
    __syncthreads();
    mamba_token(tid, b, gn, s_in, xz0, hbuf0, Win0, Wcv0, bcv0, Wxp0, Wdt0, bdt0,
                Al0, Dp0, Wo0, s_xz, s_xi, s_rg, s_dt, s_B, s_C, s_dtr, s_yp, s_y, s_ssm);
    if (tid < 64) {
      float cg = s_in[tid] + s_ssm[tid];
      s_cg[tid] = cg;
      s_in[tid] = cg;
    }
    __syncthreads();
    mamba_token(tid, b, gn, s_in, xz1, hbuf1, Win1, Wcv1, bcv1, Wxp1, Wdt1, bdt1,
                Al1, Dp1, Wo1, s_xz, s_xi, s_rg, s_dt, s_B, s_C, s_dtr, s_yp, s_y, s_ssm);
    if (tid < 64) {
      float val = s_cg[tid] + s_ssm[tid];
      float sum = val;
      #pragma unroll
      for (int m = 1; m < 64; m <<= 1) sum += __shfl_xor(sum, m);
      float mean = sum * (1.f/64.f);
      float dv = val - mean;
      float vs = dv*dv;
      #pragma unroll
      for (int m = 1; m < 64; m <<= 1) vs += __shfl_xor(vs, m);
      float oln = dv * rsqrtf(vs*(1.f/64.f) + 1e-5f) * gamma[tid] + beta[tid];
      predz[(size_t)(b*4 + p)*DM + tid] = oln;
      s_pz[p][tid] = oln;
    }
    __syncthreads();
  }

  // fused x_pred = dec(predz[0..3])
  {
    int t = tid >> 6, j = tid & 63;
    float a = bd1[j];
    const float4* zz = (const float4*)&s_pz[t][0];
    #pragma unroll 4
    for (int k4 = 0; k4 < 16; k4++) {
      float4 zv = zz[k4];
      a = fmaf(zv.x, Wd1[(k4*4+0)*64 + j], a);
      a = fmaf(zv.y, Wd1[(k4*4+1)*64 + j], a);
      a = fmaf(zv.z, Wd1[(k4*4+2)*64 + j], a);
      a = fmaf(zv.w, Wd1[(k4*4+3)*64 + j], a);
    }
    s_h[t][j] = fmaxf(a, 0.f);
  }
  __syncthreads();
  if (tid < 128) {
    int t = tid >> 5, c = tid & 31;
    float a = bd2[c];
    const float4* hh = (const float4*)&s_h[t][0];
    #pragma unroll 4
    for (int k4 = 0; k4 < 16; k4++) {
      float4 hv = hh[k4];
      a = fmaf(hv.x, Wd2[(k4*4+0)*32 + c], a);
      a = fmaf(hv.y, Wd2[(k4*4+1)*32 + c], a);
      a = fmaf(hv.z, Wd2[(k4*4+2)*32 + c], a);
      a = fmaf(hv.w, Wd2[(k4*4+3)*32 + c], a);
    }
    x_pred[(size_t)(b*4 + t)*32 + c] = a;
  }
}

extern "C" void kernel_launch(void* const* d_in, const int* in_sizes, int n_in,
                              void* d_out, int out_size, void* d_ws, size_t ws_size,
                              hipStream_t stream)
{
  (void)in_sizes; (void)n_in; (void)out_size; (void)ws_size;
  const float* x     = (const float*)d_in[0];
  const float* We1   = (const float*)d_in[1];
  const float* be1   = (const float*)d_in[2];
  const float* We2   = (const float*)d_in[3];
  const float* be2   = (const float*)d_in[4];
  const float* Wd1   = (const float*)d_in[5];
  const float* bd1   = (const float*)d_in[6];
  const float* Wd2   = (const float*)d_in[7];
  const float* bd2   = (const float*)d_in[8];
  const float* Win   = (const float*)d_in[9];
  const float* Wconv = (const float*)d_in[10];
  const float* bconv = (const float*)d_in[11];
  const float* Wxp   = (const float*)d_in[12];
  const float* Wdt   = (const float*)d_in[13];
  const float* bdt   = (const float*)d_in[14];
  const float* Alog  = (const float*)d_in[15];
  const float* Dp    = (const float*)d_in[16];
  const float* Wout  = (const float*)d_in[17];
  const float* gamma = (const float*)d_in[18];
  const float* beta  = (const float*)d_in[19];

  float* o      = (float*)d_out;
  float* x_rec  = o;                 // 8*1024*32
  float* x_dyn  = o + 262144;        // 8*1024*32
  float* x_pred = o + 524288;        // 8*4*32
  float* z      = o + 525312;        // 8*1024*64
  float* zdyn   = o + 1049600;       // 8*1024*64

  float* w      = (float*)d_ws;
  float* xi0    = w;                            // 1048576
  float* resg0  = xi0   + 1048576;              // 1048576
  float2* dd0   = (float2*)(resg0 + 1048576);   // 2097152 floats
  float* Bb0    = resg0 + 1048576 + 2097152;    // 262144
  float* Cb0    = Bb0   + 262144;               // 262144
  float* xi1    = Cb0   + 262144;               // 1048576
  float* resg1  = xi1   + 1048576;              // 1048576
  float2* dd1   = (float2*)(resg1 + 1048576);   // 2097152 floats
  float* Bb1    = resg1 + 1048576 + 2097152;    // 262144
  float* Cb1    = Bb1   + 262144;               // 262144
  float* ys     = Cb1   + 262144;               // 1048576
  float2* hc    = (float2*)(ys + 1048576);      // 1048576 floats
  float* predz  = ys + 1048576 + 1048576;       // 2048
  float* xz0    = predz + 2048;                 // 1052672 (8*1028*128)
  float* xz1    = xz0   + 1052672;              // 1052672
  float* curg   = xz1   + 1052672;              // 526336 (8*1028*64)
  float* hbuf0  = curg  + 526336;               // 32768
  float* hbuf1  = hbuf0 + 32768;                // 32768

  const float* Win0 = Win,   *Win1 = Win + 64*256;
  const float* Wcv0 = Wconv, *Wcv1 = Wconv + 128*4;
  const float* bcv0 = bconv, *bcv1 = bconv + 128;
  const float* Wxp0 = Wxp,   *Wxp1 = Wxp + 128*68;
  const float* Wdt0 = Wdt,   *Wdt1 = Wdt + 4*128;
  const float* bdt0 = bdt,   *bdt1 = bdt + 128;
  const float* Al0  = Alog,  *Al1  = Alog + 128*32;
  const float* Dp0  = Dp,    *Dp1  = Dp + 128;
  const float* Wo0  = Wout,  *Wo1  = Wout + 128*64;

  // encoder + reconstruction decoder
  enc_xrec_kernel<<<dim3(512), dim3(256), 0, stream>>>(x, We1, be1, We2, be2, Wd1, bd1, Wd2, bd2, z, x_rec);

  // ---- block-0 global pipeline (once) ----
  pre_kernel<<<dim3(1024), dim3(256), 0, stream>>>(z, TLEN,
                                                   Win0, Wcv0, bcv0, Wxp0, Wdt0, bdt0,
                                                   xi0, resg0, dd0, Bb0, Cb0, xz0);
  scan1_kernel<<<dim3(4096), dim3(128), 0, stream>>>(dd0, Bb0, Al0, hc);
  scan3_kernel<<<dim3(4096), dim3(128), 0, stream>>>(dd0, Bb0, Cb0, Al0, hc, ys, hbuf0);
  post_kernel<<<dim3(1024), dim3(256), 0, stream>>>(ys, xi0, resg0, Dp0, Wo0,
                                                    z, TLEN, curg,
                                                    (float*)nullptr, (float*)nullptr,
                                                    (const float*)nullptr, (const float*)nullptr,
                                                    (const float*)nullptr, (const float*)nullptr,
                                                    (const float*)nullptr, (const float*)nullptr,
                                                    (float*)nullptr, 0);

  // ---- block-1 global pipeline (once): input curg; fused LN + x_dyn decoder ----
  pre_kernel<<<dim3(1024), dim3(256), 0, stream>>>(curg, GEXT,
                                                   Win1, Wcv1, bcv1, Wxp1, Wdt1, bdt1,
                                                   xi1, resg1, dd1, Bb1, Cb1, xz1);
  scan1_kernel<<<dim3(4096), dim3(128), 0, stream>>>(dd1, Bb1, Al1, hc);
  scan3_kernel<<<dim3(4096), dim3(128), 0, stream>>>(dd1, Bb1, Cb1, Al1, hc, ys, hbuf1);
  post_kernel<<<dim3(1024), dim3(256), 0, stream>>>(ys, xi1, resg1, Dp1, Wo1,
                                                    curg, GEXT, (float*)nullptr,
                                                    zdyn, predz, gamma, beta,
                                                    Wd1, bd1, Wd2, bd2, x_dyn, 1);

  // ---- pred passes 1..3 + x_pred decoder: ONE kernel ----
  ext_all_kernel<<<dim3(8), dim3(256), 0, stream>>>(predz, xz0, xz1, hbuf0, hbuf1,
      Win0, Wcv0, bcv0, Wxp0, Wdt0, bdt0, Al0, Dp0, Wo0,
      Win1, Wcv1, bcv1, Wxp1, Wdt1, bdt1, Al1, Dp1, Wo1,
      gamma, beta, Wd1, bd1, Wd2, bd2, x_pred);
}

// Round 17
// 228.647 us; speedup vs baseline: 1.0388x; 1.0388x over previous
//
#include <hip/hip_runtime.h>

#define BSZ 8
#define TLEN 1024
#define DM 64
#define DI 128
#define DS 32
#define NCHUNK 16
#define CLEN 64
#define GEXT 1028   // 1024 z-tokens + up to 4 appended pred tokens (global token axis)

__device__ __forceinline__ float siluf(float x) { return x / (1.f + expf(-x)); }
__device__ __forceinline__ float softplusf(float x) { return (x > 20.f) ? x : log1pf(expf(x)); }

// ================= shared pre tail: conv/silu/xproj/dt from s_xz(11x64 LDS) =================
// s_in: 11 rows x 64 (xz input rows, halo-complete, zero-padded). Writes xi/resg/dd/B/C (+xz last tile).
__device__ __forceinline__ void pre_tail(
    int tid, int b, int t0, const float* __restrict__ s_zrows,
    float* __restrict__ s_xi, float* __restrict__ s_dtr,
    const float* __restrict__ Win, const float* __restrict__ Wconv, const float* __restrict__ bconv,
    const float* __restrict__ Wxproj, const float* __restrict__ Wdt, const float* __restrict__ bdt,
    float* __restrict__ xibuf, float* __restrict__ resgbuf,
    float2* __restrict__ ddbuf, float* __restrict__ Bbuf, float* __restrict__ Cbuf,
    float* __restrict__ xzout)
{
  float acc[11];
  #pragma unroll
  for (int r = 0; r < 11; r++) acc[r] = 0.f;
  #pragma unroll
  for (int k4 = 0; k4 < 16; k4++) {
    float w0 = Win[(k4*4+0)*256 + tid];
    float w1 = Win[(k4*4+1)*256 + tid];
    float w2 = Win[(k4*4+2)*256 + tid];
    float w3 = Win[(k4*4+3)*256 + tid];
    #pragma unroll
    for (int r = 0; r < 11; r++) {
      float4 xv = *(const float4*)&s_zrows[r*64 + k4*4];
      acc[r] = fmaf(xv.x, w0, acc[r]);
      acc[r] = fmaf(xv.y, w1, acc[r]);
      acc[r] = fmaf(xv.z, w2, acc[r]);
      acc[r] = fmaf(xv.w, w3, acc[r]);
    }
  }

  if (tid < 128) {
    float4 wc = *(const float4*)&Wconv[tid*4];
    float bc = bconv[tid];
    const bool store_xz = (t0 == TLEN-8);   // only ext_all's conv (tokens >=1021) reads xz
    #pragma unroll
    for (int tau = 0; tau < 8; tau++) {
      float v = bc;
      v = fmaf(acc[tau+0], wc.x, v);
      v = fmaf(acc[tau+1], wc.y, v);
      v = fmaf(acc[tau+2], wc.z, v);
      v = fmaf(acc[tau+3], wc.w, v);
      float xiv = siluf(v);
      s_xi[tau*128 + tid] = xiv;
      xibuf[((size_t)b*TLEN + t0 + tau)*DI + tid] = xiv;
      if (store_xz) xzout[((size_t)b*GEXT + t0 + tau)*128 + tid] = acc[tau+3];
    }
  } else {
    int d = tid - 128;
    #pragma unroll
    for (int tau = 0; tau < 8; tau++)
      resgbuf[((size_t)b*TLEN + t0 + tau)*DI + d] = siluf(acc[tau+3]);
  }
  __syncthreads();
  {
    const int wv = tid >> 6, c = tid & 63;
    float a0 = 0.f, a1 = 0.f;
    const float4* x0 = (const float4*)&s_xi[(wv*2+0)*128];
    const float4* x1 = (const float4*)&s_xi[(wv*2+1)*128];
    #pragma unroll 4
    for (int k4 = 0; k4 < 32; k4++) {
      float wq0 = Wxproj[(k4*4+0)*68 + 4 + c];
      float wq1 = Wxproj[(k4*4+1)*68 + 4 + c];
      float wq2 = Wxproj[(k4*4+2)*68 + 4 + c];
      float wq3 = Wxproj[(k4*4+3)*68 + 4 + c];
      float4 v0 = x0[k4], v1 = x1[k4];
      a0 = fmaf(v0.x,wq0, fmaf(v0.y,wq1, fmaf(v0.z,wq2, fmaf(v0.w,wq3, a0))));
      a1 = fmaf(v1.x,wq0, fmaf(v1.y,wq1, fmaf(v1.z,wq2, fmaf(v1.w,wq3, a1))));
    }
    size_t tb = (size_t)b*TLEN + t0 + wv*2;
    if (c < 32) {
      Bbuf[(tb+0)*DS + c] = a0; Bbuf[(tb+1)*DS + c] = a1;
    } else {
      int cc = c - 32;
      Cbuf[(tb+0)*DS + cc] = a0; Cbuf[(tb+1)*DS + cc] = a1;
    }
  }
  if (tid < 32) {
    int tau = tid >> 2, cc = tid & 3;
    float a = 0.f;
    const float4* xx = (const float4*)&s_xi[tau*128];
    #pragma unroll 4
    for (int k4 = 0; k4 < 32; k4++) {
      float4 v = xx[k4];
      a = fmaf(v.x, Wxproj[(k4*4+0)*68 + cc], a);
      a = fmaf(v.y, Wxproj[(k4*4+1)*68 + cc], a);
      a = fmaf(v.z, Wxproj[(k4*4+2)*68 + cc], a);
      a = fmaf(v.w, Wxproj[(k4*4+3)*68 + cc], a);
    }
    s_dtr[tau*4 + cc] = a;
  }
  __syncthreads();
  #pragma unroll
  for (int u = 0; u < 4; u++) {
    int i = tid + u*256;
    int tau = i >> 7, d = i & 127;
    float a = bdt[d];
    #pragma unroll
    for (int r = 0; r < 4; r++) a = fmaf(s_dtr[tau*4 + r], Wdt[r*128 + d], a);
    float dtv = softplusf(a);
    ddbuf[((size_t)b*TLEN + t0 + tau)*DI + d] = make_float2(dtv, dtv * s_xi[i]);
  }
}

// ================ fusedA: enc(11 tok incl halo) + z/x_rec writes + pre0 tail ================
__global__ __launch_bounds__(256,4) void encpre_kernel(
    const float* __restrict__ x,
    const float* __restrict__ We1, const float* __restrict__ be1,
    const float* __restrict__ We2, const float* __restrict__ be2,
    const float* __restrict__ Wd1, const float* __restrict__ bd1,
    const float* __restrict__ Wd2, const float* __restrict__ bd2,
    float* __restrict__ zout, float* __restrict__ x_rec,
    const float* __restrict__ Win, const float* __restrict__ Wconv, const float* __restrict__ bconv,
    const float* __restrict__ Wxproj, const float* __restrict__ Wdt, const float* __restrict__ bdt,
    float* __restrict__ xibuf, float* __restrict__ resgbuf,
    float2* __restrict__ ddbuf, float* __restrict__ Bbuf, float* __restrict__ Cbuf,
    float* __restrict__ xzout)
{
  __shared__ float s_x[11*32];
  __shared__ float s_h1[11*64];
  __shared__ float s_z[11*64];
  __shared__ float s_h2[8*64];
  __shared__ float s_xi[8*128];
  __shared__ float s_dtr[8*4];
  const int tid = threadIdx.x;
  const int b  = blockIdx.x >> 7;
  const int t0 = (blockIdx.x & 127) * 8;

  for (int i = tid; i < 11*32; i += 256) {
    int r = i >> 5, c = i & 31;
    int tg = t0 - 3 + r;
    s_x[i] = (tg >= 0) ? x[(size_t)(b*TLEN + tg)*32 + c] : 0.f;
  }
  __syncthreads();
  // h1 = relu(x@We1 + be1), 11x64 jobs
  {
    const int j = tid & 63, tg4 = tid >> 6;
    #pragma unroll
    for (int q = 0; q < 3; q++) {
      int r = tg4 + 4*q;
      if (r < 11) {
        float a = be1[j];
        const float4* xx = (const float4*)&s_x[r*32];
        #pragma unroll
        for (int k4 = 0; k4 < 8; k4++) {
          float4 v = xx[k4];
          a = fmaf(v.x, We1[(k4*4+0)*64 + j], a);
          a = fmaf(v.y, We1[(k4*4+1)*64 + j], a);
          a = fmaf(v.z, We1[(k4*4+2)*64 + j], a);
          a = fmaf(v.w, We1[(k4*4+3)*64 + j], a);
        }
        s_h1[r*64 + j] = fmaxf(a, 0.f);
      }
    }
  }
  __syncthreads();
  // z = h1@We2 + be2; zero halo rows when t0==0 (z-pad == xz-pad); write owned tokens
  {
    const int j = tid & 63, tg4 = tid >> 6;
    #pragma unroll
    for (int q = 0; q < 3; q++) {
      int r = tg4 + 4*q;
      if (r < 11) {
        float a;
        if (t0 == 0 && r < 3) {
          a = 0.f;
        } else {
          a = be2[j];
          const float4* hh = (const float4*)&s_h1[r*64];
          #pragma unroll 4
          for (int k4 = 0; k4 < 16; k4++) {
            float4 v = hh[k4];
            a = fmaf(v.x, We2[(k4*4+0)*64 + j], a);
            a = fmaf(v.y, We2[(k4*4+1)*64 + j], a);
            a = fmaf(v.z, We2[(k4*4+2)*64 + j], a);
            a = fmaf(v.w, We2[(k4*4+3)*64 + j], a);
          }
        }
        s_z[r*64 + j] = a;
        if (r >= 3) zout[(size_t)(b*TLEN + t0 + r-3)*64 + j] = a;
      }
    }
  }
  __syncthreads();
  // h2 = relu(z@Wd1+bd1) for 8 owned tokens
  {
    const int j = tid & 63, tg4 = tid >> 6;
    #pragma unroll
    for (int q = 0; q < 2; q++) {
      int t = tg4 + 4*q;
      float a = bd1[j];
      const float4* zz = (const float4*)&s_z[(t+3)*64];
      #pragma unroll 4
      for (int k4 = 0; k4 < 16; k4++) {
        float4 v = zz[k4];
        a = fmaf(v.x, Wd1[(k4*4+0)*64 + j], a);
        a = fmaf(v.y, Wd1[(k4*4+1)*64 + j], a);
        a = fmaf(v.z, Wd1[(k4*4+2)*64 + j], a);
        a = fmaf(v.w, Wd1[(k4*4+3)*64 + j], a);
      }
      s_h2[t*64 + j] = fmaxf(a, 0.f);
    }
  }
  __syncthreads();
  // x_rec = h2@Wd2 + bd2
  {
    int t = tid >> 5, c = tid & 31;
    float a = bd2[c];
    const float4* hh = (const float4*)&s_h2[t*64];
    #pragma unroll 4
    for (int k4 = 0; k4 < 16; k4++) {
      float4 v = hh[k4];
      a = fmaf(v.x, Wd2[(k4*4+0)*32 + c], a);
      a = fmaf(v.y, Wd2[(k4*4+1)*32 + c], a);
      a = fmaf(v.z, Wd2[(k4*4+2)*32 + c], a);
      a = fmaf(v.w, Wd2[(k4*4+3)*32 + c], a);
    }
    x_rec[(size_t)(b*TLEN + t0 + t)*32 + c] = a;
  }
  // pre tail reads s_z (stable since its sync)
  pre_tail(tid, b, t0, s_z, s_xi, s_dtr,
           Win, Wconv, bconv, Wxproj, Wdt, bdt,
           xibuf, resgbuf, ddbuf, Bbuf, Cbuf, xzout);
}

// ================ fusedB: post0 (curg = z + gated(ys)@Wout) + pre1 tail ================
__global__ __launch_bounds__(256,4) void postpre_kernel(
    const float* __restrict__ ys, const float* __restrict__ xi0, const float* __restrict__ resg0,
    const float* __restrict__ Dp0, const float* __restrict__ Wo0,
    const float* __restrict__ zsrc,
    const float* __restrict__ Win, const float* __restrict__ Wconv, const float* __restrict__ bconv,
    const float* __restrict__ Wxproj, const float* __restrict__ Wdt, const float* __restrict__ bdt,
    float* __restrict__ curg,
    float* __restrict__ xibuf, float* __restrict__ resgbuf,
    float2* __restrict__ ddbuf, float* __restrict__ Bbuf, float* __restrict__ Cbuf,
    float* __restrict__ xzout)
{
  __shared__ float s_y[11*128];
  __shared__ float s_cur[11*64];
  __shared__ float s_xi[8*128];
  __shared__ float s_dtr[8*4];
  const int tid = threadIdx.x;
  const int b  = blockIdx.x >> 7;
  const int t0 = (blockIdx.x & 127) * 8;

  for (int i = tid; i < 11*128; i += 256) {
    int r = i >> 7, d = i & 127;
    int tg = t0 - 3 + r;
    float v = 0.f;
    if (tg >= 0) {
      size_t g = (size_t)(b*TLEN + tg)*DI + d;
      v = (ys[g] + xi0[g]*Dp0[d]) * resg0[g];
    }
    s_y[i] = v;
  }
  __syncthreads();
  // curg rows (halo recomputed; owned 8 written to global)
  {
    const int c = tid & 63, tg4 = tid >> 6;
    #pragma unroll
    for (int q = 0; q < 3; q++) {
      int r = tg4 + 4*q;
      if (r < 11) {
        int tg = t0 - 3 + r;
        float val = 0.f;
        if (tg >= 0) {
          float a = 0.f;
          const float4* yy = (const float4*)&s_y[r*128];
          #pragma unroll 4
          for (int k4 = 0; k4 < 32; k4++) {
            float4 vv = yy[k4];
            a = fmaf(vv.x, Wo0[(k4*4+0)*64 + c], a);
            a = fmaf(vv.y, Wo0[(k4*4+1)*64 + c], a);
            a = fmaf(vv.z, Wo0[(k4*4+2)*64 + c], a);
            a = fmaf(vv.w, Wo0[(k4*4+3)*64 + c], a);
          }
          val = zsrc[(size_t)(b*TLEN + tg)*DM + c] + a;
          if (r >= 3) curg[((size_t)b*GEXT + tg)*DM + c] = val;
        }
        s_cur[r*64 + c] = val;
      }
    }
  }
  __syncthreads();
  pre_tail(tid, b, t0, s_cur, s_xi, s_dtr,
           Win, Wconv, bconv, Wxproj, Wdt, bdt,
           xibuf, resgbuf, ddbuf, Bbuf, Cbuf, xzout);
}

// B/C chunk swizzle (r4): breaks the stride-68 8-way conflict down to <=2-way.
#define BSWZ(row3) (((row3)&3)<<1)

// XCD work swizzle (r9): consecutive work-ids share blockIdx%8 -> co-XCD L2 reuse.
__device__ __forceinline__ int xcd_wid_4096() {
  return (blockIdx.x >> 3) | ((blockIdx.x & 7) << 9);
}

// ---------------- scan phase 1: per-chunk local scan from h=0; emits (h_end, decay) ----------------
__global__ __launch_bounds__(128) void scan1_kernel(
    const float2* __restrict__ ddbuf, const float* __restrict__ Bbuf,
    const float* __restrict__ Alog, float2* __restrict__ hc)
{
  __shared__ float2 s_dd[4][CLEN];
  __shared__ float  s_Bt[32][68];
  const int tid = threadIdx.x;
  const int ch = tid >> 5, s = tid & 31;
  const int wid = xcd_wid_4096();
  const int dg = wid & 31;
  const int c  = (wid >> 5) & 15;
  const int b  = wid >> 9;
  const int d0 = dg * 4;
  const float A = -__expf(Alog[(d0 + ch)*DS + s]);
  const float2* ddg = ddbuf + ((size_t)b*TLEN + c*CLEN)*DI + d0;
  const float*  Bg  = Bbuf  + ((size_t)b*TLEN + c*CLEN)*DS;
  {
    int t = tid >> 1, half = tid & 1;
    float4 rdd = *(const float4*)((const float*)(ddg + (size_t)t*DI) + half*4);
    s_dd[2*half+0][t] = make_float2(rdd.x, rdd.y);
    s_dd[2*half+1][t] = make_float2(rdd.z, rdd.w);
    #pragma unroll
    for (int j = 0; j < 4; j++) {
      int q = tid + 128*j; int tt = q >> 3, k4 = q & 7;
      float4 rB = *(const float4*)(Bg + tt*DS + k4*4);
      int cp = (((tt>>2) ^ BSWZ(k4>>1)) << 2) + (tt & 3);
      s_Bt[k4*4+0][cp] = rB.x; s_Bt[k4*4+1][cp] = rB.y;
      s_Bt[k4*4+2][cp] = rB.z; s_Bt[k4*4+3][cp] = rB.w;
    }
  }
  __syncthreads();
  float h = 0.f, dts = 0.f;
  const float4* dd4 = (const float4*)&s_dd[ch][0];
  const float4* bt4 = (const float4*)&s_Bt[s][0];
  const int swr = BSWZ(s>>3);
  #pragma unroll
  for (int j = 0; j < 8; j++) {
    float4 e0 = dd4[4*j+0], e1 = dd4[4*j+1], e2 = dd4[4*j+2], e3 = dd4[4*j+3];
    float4 bb0 = bt4[(2*j)^swr], bb1 = bt4[(2*j+1)^swr];
    h = fmaf(__expf(e0.x*A), h, e0.y*bb0.x);
    h = fmaf(__expf(e0.z*A), h, e0.w*bb0.y);
    h = fmaf(__expf(e1.x*A), h, e1.y*bb0.z);
    h = fmaf(__expf(e1.z*A), h, e1.w*bb0.w);
    h = fmaf(__expf(e2.x*A), h, e2.y*bb1.x);
    h = fmaf(__expf(e2.z*A), h, e2.w*bb1.y);
    h = fmaf(__expf(e3.x*A), h, e3.y*bb1.z);
    h = fmaf(__expf(e3.z*A), h, e3.w*bb1.w);
    dts += (e0.x + e0.z) + (e1.x + e1.z) + (e2.x + e2.z) + (e3.x + e3.z);
  }
  int o = ((b*NCHUNK + c)*DI + d0 + ch)*DS + s;
  hc[o] = make_float2(h, __expf(A*dts));
}

// ---------------- scan phase 3: prefix-combine + rescan chunk, emit y + h(1023) ----------------
__global__ __launch_bounds__(128) void scan3_kernel(
    const float2* __restrict__ ddbuf, const float* __restrict__ Bbuf, const float* __restrict__ Cbuf,
    const float* __restrict__ Alog, const float2* __restrict__ hc, float* __restrict__ ysbuf,
    float* __restrict__ hout)
{
  __shared__ float2 s_dd[4][CLEN];
  __shared__ float  s_Bt[32][68];
  __shared__ float  s_Ct[32][68];
  __shared__ float  s_p[128][33];
  const int tid = threadIdx.x;
  const int ch = tid >> 5, s = tid & 31;
  const int wid = xcd_wid_4096();
  const int dg = wid & 31;
  const int c  = (wid >> 5) & 15;
  const int b  = wid >> 9;
  const int d0 = dg * 4;
  const float A = -__expf(Alog[(d0 + ch)*DS + s]);
  const float2* ddg = ddbuf + ((size_t)b*TLEN + c*CLEN)*DI + d0;
  const float*  Bg  = Bbuf  + ((size_t)b*TLEN + c*CLEN)*DS;
  const float*  Cg  = Cbuf  + ((size_t)b*TLEN + c*CLEN)*DS;

  const int ob = (d0 + ch)*DS + s;
  float2 v[15];
  #pragma unroll
  for (int q = 0; q < 15; q++) v[q] = hc[(size_t)(b*NCHUNK + q)*4096 + ob];

  {
    int t = tid >> 1, half = tid & 1;
    float4 rdd = *(const float4*)((const float*)(ddg + (size_t)t*DI) + half*4);
    s_dd[2*half+0][t] = make_float2(rdd.x, rdd.y);
    s_dd[2*half+1][t] = make_float2(rdd.z, rdd.w);
    #pragma unroll
    for (int j = 0; j < 4; j++) {
      int q = tid + 128*j; int tt = q >> 3, k4 = q & 7;
      float4 rB = *(const float4*)(Bg + tt*DS + k4*4);
      float4 rC = *(const float4*)(Cg + tt*DS + k4*4);
      int cp = (((tt>>2) ^ BSWZ(k4>>1)) << 2) + (tt & 3);
      s_Bt[k4*4+0][cp] = rB.x; s_Bt[k4*4+1][cp] = rB.y;
      s_Bt[k4*4+2][cp] = rB.z; s_Bt[k4*4+3][cp] = rB.w;
      s_Ct[k4*4+0][cp] = rC.x; s_Ct[k4*4+1][cp] = rC.y;
      s_Ct[k4*4+2][cp] = rC.z; s_Ct[k4*4+3][cp] = rC.w;
    }
  }
  float h = 0.f;
  #pragma unroll
  for (int q = 0; q < 15; q++)
    if (q < c) h = fmaf(v[q].y, h, v[q].x);
  __syncthreads();

  const float4* dd4 = (const float4*)&s_dd[ch][0];
  const float4* bt4 = (const float4*)&s_Bt[s][0];
  const float4* ct4 = (const float4*)&s_Ct[s][0];
  const int swr = BSWZ(s>>3);
  float* pr = &s_p[tid][0];
  #pragma unroll
  for (int half = 0; half < 2; half++) {
    #pragma unroll
    for (int j = 0; j < 4; j++) {
      const int jj = half*4 + j;
      float4 e0 = dd4[4*jj+0], e1 = dd4[4*jj+1], e2 = dd4[4*jj+2], e3 = dd4[4*jj+3];
      float4 bb0 = bt4[(2*jj)^swr], bb1 = bt4[(2*jj+1)^swr];
      float4 cc0 = ct4[(2*jj)^swr], cc1 = ct4[(2*jj+1)^swr];
      h = fmaf(__expf(e0.x*A), h, e0.y*bb0.x); pr[8*j+0] = h*cc0.x;
      h = fmaf(__expf(e0.z*A), h, e0.w*bb0.y); pr[8*j+1] = h*cc0.y;
      h = fmaf(__expf(e1.x*A), h, e1.y*bb0.z); pr[8*j+2] = h*cc0.z;
      h = fmaf(__expf(e1.z*A), h, e1.w*bb0.w); pr[8*j+3] = h*cc0.w;
      h = fmaf(__expf(e2.x*A), h, e2.y*bb1.x); pr[8*j+4] = h*cc1.x;
      h = fmaf(__expf(e2.z*A), h, e2.w*bb1.y); pr[8*j+5] = h*cc1.y;
      h = fmaf(__expf(e3.x*A), h, e3.y*bb1.z); pr[8*j+6] = h*cc1.z;
      h = fmaf(__expf(e3.z*A), h, e3.w*bb1.w); pr[8*j+7] = h*cc1.w;
    }
    __syncthreads();
    {
      const int ch2 = tid & 3;
      const int tq  = tid >> 2;
      float a = 0.f;
      #pragma unroll
      for (int s2 = 0; s2 < 32; s2++) a += s_p[ch2*32 + s2][tq];
      ysbuf[(size_t)(b*TLEN + c*CLEN + half*32 + tq)*DI + d0 + ch2] = a;
    }
    __syncthreads();
  }
  if (c == 15) hout[(size_t)(b*DI + d0 + ch)*DS + s] = h;
}

// ---------------- post1: 8 tokens/block, 1024 blocks; LN -> zdyn/predz0 + fused x_dyn decoder ----
__global__ __launch_bounds__(256,4) void post_kernel(
    const float* __restrict__ ysbuf, const float* __restrict__ xibuf, const float* __restrict__ resgbuf,
    const float* __restrict__ Dp, const float* __restrict__ Wout,
    const float* __restrict__ basebuf, int base_stride,
    float* __restrict__ zdyn, float* __restrict__ predz,
    const float* __restrict__ gamma, const float* __restrict__ beta,
    const float* __restrict__ Wd1, const float* __restrict__ bd1,
    const float* __restrict__ Wd2, const float* __restrict__ bd2,
    float* __restrict__ xdyn)
{
  __shared__ float s_y[8*128];
  __shared__ float s_z[8*64];
  __shared__ float s_h[8*64];
  const int tid = threadIdx.x;
  const int b  = blockIdx.x >> 7;
  const int t0 = (blockIdx.x & 127) * 8;
  #pragma unroll
  for (int u = 0; u < 4; u++) {
    int i = tid + u*256;
    size_t g = (size_t)(b*TLEN + t0)*DI + i;
    s_y[i] = (ysbuf[g] + xibuf[g]*Dp[i & 127]) * resgbuf[g];
  }
  __syncthreads();
  #pragma unroll
  for (int u = 0; u < 2; u++) {
    int i = tid + u*256;
    int tau = i >> 6, c = i & 63;
    float a = 0.f;
    const float4* yy = (const float4*)&s_y[tau*128];
    #pragma unroll 4
    for (int k4 = 0; k4 < 32; k4++) {
      float4 vv = yy[k4];
      a = fmaf(vv.x, Wout[(k4*4+0)*64 + c], a);
      a = fmaf(vv.y, Wout[(k4*4+1)*64 + c], a);
      a = fmaf(vv.z, Wout[(k4*4+2)*64 + c], a);
      a = fmaf(vv.w, Wout[(k4*4+3)*64 + c], a);
    }
    float base = basebuf[((size_t)b*base_stride + t0 + tau)*DM + c];
    float val = base + a;
    float sum = val;
    #pragma unroll
    for (int m = 1; m < 64; m <<= 1) sum += __shfl_xor(sum, m);
    float mean = sum * (1.f/64.f);
    float dv = val - mean;
    float vs = dv*dv;
    #pragma unroll
    for (int m = 1; m < 64; m <<= 1) vs += __shfl_xor(vs, m);
    float oln = dv * rsqrtf(vs*(1.f/64.f) + 1e-5f) * gamma[c] + beta[c];
    zdyn[(size_t)(b*TLEN + t0 + tau)*DM + c] = oln;
    s_z[tau*64 + c] = oln;
    if (t0 + tau == TLEN-1) predz[(size_t)(b*4 + 0)*DM + c] = oln;
  }
  __syncthreads();
  #pragma unroll
  for (int u = 0; u < 2; u++) {
    int i = tid + u*256;
    int t = i >> 6, j = i & 63;
    float a = bd1[j];
    const float4* zz = (const float4*)&s_z[t*64];
    #pragma unroll 4
    for (int k4 = 0; k4 < 16; k4++) {
      float4 zv = zz[k4];
      a = fmaf(zv.x, Wd1[(k4*4+0)*64 + j], a);
      a = fmaf(zv.y, Wd1[(k4*4+1)*64 + j], a);
      a = fmaf(zv.z, Wd1[(k4*4+2)*64 + j], a);
      a = fmaf(zv.w, Wd1[(k4*4+3)*64 + j], a);
    }
    s_h[i] = fmaxf(a, 0.f);
  }
  __syncthreads();
  {
    int t = tid >> 5, c = tid & 31;
    float a = bd2[c];
    const float4* hh = (const float4*)&s_h[t*64];
    #pragma unroll 4
    for (int k4 = 0; k4 < 16; k4++) {
      float4 hv = hh[k4];
      a = fmaf(hv.x, Wd2[(k4*4+0)*32 + c], a);
      a = fmaf(hv.y, Wd2[(k4*4+1)*32 + c], a);
      a = fmaf(hv.z, Wd2[(k4*4+2)*32 + c], a);
      a = fmaf(hv.w, Wd2[(k4*4+3)*32 + c], a);
    }
    xdyn[(size_t)(b*TLEN + t0 + t)*32 + c] = a;
  }
}

// ---------------- one-token mamba step (shared helper for ext_all) ----------------
__device__ __forceinline__ void mamba_token(
    int tid, int b, int gn, const float* __restrict__ s_in,
    float* __restrict__ xzg, float* __restrict__ hbuf,
    const float* __restrict__ Win, const float* __restrict__ Wcv, const float* __restrict__ bcv,
    const float* __restrict__ Wxp, const float* __restrict__ Wdt, const float* __restrict__ bdt,
    const float* __restrict__ Al, const float* __restrict__ Dpp, const float* __restrict__ Wo,
    float* __restrict__ s_xz, float* __restrict__ s_xi, float* __restrict__ s_rg,
    float* __restrict__ s_dt, float* __restrict__ s_B, float* __restrict__ s_C,
    float* __restrict__ s_dtr, float* __restrict__ s_yp, float* __restrict__ s_y,
    float* __restrict__ s_ssm)
{
  {
    float a = 0.f;
    #pragma unroll
    for (int k = 0; k < 64; k++) a = fmaf(s_in[k], Win[k*256 + tid], a);
    s_xz[tid] = a;
  }
  __syncthreads();
  if (tid < 128) {
    xzg[((size_t)b*GEXT + gn)*128 + tid] = s_xz[tid];
    float acc = bcv[tid];
    acc = fmaf(xzg[((size_t)b*GEXT + gn-3)*128 + tid], Wcv[tid*4+0], acc);
    acc = fmaf(xzg[((size_t)b*GEXT + gn-2)*128 + tid], Wcv[tid*4+1], acc);
    acc = fmaf(xzg[((size_t)b*GEXT + gn-1)*128 + tid], Wcv[tid*4+2], acc);
    acc = fmaf(s_xz[tid], Wcv[tid*4+3], acc);
    s_xi[tid] = siluf(acc);
    s_rg[tid] = siluf(s_xz[128 + tid]);
  }
  __syncthreads();
  if (tid < 68) {
    float a = 0.f;
    #pragma unroll 4
    for (int k = 0; k < 128; k++) a = fmaf(s_xi[k], Wxp[k*68 + tid], a);
    if (tid < 4)       s_dtr[tid] = a;
    else if (tid < 36) s_B[tid-4] = a;
    else               s_C[tid-36] = a;
  }
  __syncthreads();
  if (tid < 128) {
    float a = bdt[tid];
    #pragma unroll
    for (int r = 0; r < 4; r++) a = fmaf(s_dtr[r], Wdt[r*128 + tid], a);
    s_dt[tid] = softplusf(a);
  }
  __syncthreads();
  {
    int d = tid >> 1, sh = (tid & 1) * 16;
    float dtd = s_dt[d], dtxd = dtd * s_xi[d];
    float yp = 0.f;
    #pragma unroll
    for (int q = 0; q < 16; q++) {
      int s = sh + q;
      size_t oo = (size_t)(b*DI + d)*DS + s;
      float A = -__expf(Al[d*DS + s]);
      float h = hbuf[oo];
      h = fmaf(__expf(dtd*A), h, dtxd*s_B[s]);
      hbuf[oo] = h;
      yp = fmaf(s_C[s], h, yp);
    }
    s_yp[(tid & 1)*128 + d] = yp;
  }
  __syncthreads();
  if (tid < 128) s_y[tid] = ((s_yp[tid] + s_yp[128 + tid]) + s_xi[tid]*Dpp[tid]) * s_rg[tid];
  __syncthreads();
  if (tid < 64) {
    float a = 0.f;
    #pragma unroll 4
    for (int k = 0; k < 128; k++) a = fmaf(s_y[k], Wo[k*64 + tid], a);
    s_ssm[tid] = a;
  }
  __syncthreads();
}

// ---------------- ext_all: passes 1..3 in ONE 8-block kernel + fused x_pred decoder ----------------
__global__ __launch_bounds__(256) void ext_all_kernel(
    float* __restrict__ predz,
    float* __restrict__ xz0, float* __restrict__ xz1,
    float* __restrict__ hbuf0, float* __restrict__ hbuf1,
    const float* __restrict__ Win0, const float* __restrict__ Wcv0, const float* __restrict__ bcv0,
    const float* __restrict__ Wxp0, const float* __restrict__ Wdt0, const float* __restrict__ bdt0,
    const float* __restrict__ Al0, const float* __restrict__ Dp0, const float* __restrict__ Wo0,
    const float* __restrict__ Win1, const float* __restrict__ Wcv1, const float* __restrict__ bcv1,
    const float* __restrict__ Wxp1, const float* __restrict__ Wdt1, const float* __restrict__ bdt1,
    const float* __restrict__ Al1, const float* __restrict__ Dp1, const float* __restrict__ Wo1,
    const float* __restrict__ gamma, const float* __restrict__ beta,
    const float* __restrict__ Wd1, const float* __restrict__ bd1,
    const float* __restrict__ Wd2, const float* __restrict__ bd2,
    float* __restrict__ x_pred)
{
  __shared__ float s_in[64], s_cg[64], s_ssm[64];
  __shared__ float s_xz[256], s_yp[256];
  __shared__ float s_xi[128], s_rg[128], s_dt[128], s_y[128];
  __shared__ float s_B[32], s_C[32], s_dtr[4];
  __shared__ float s_pz[4][64];
  __shared__ float s_h[4][64];
  const int tid = threadIdx.x;
  const int b = blockIdx.x;

  if (tid < 64) s_pz[0][tid] = predz[(size_t)(b*4 + 0)*DM + tid];
  __syncthreads();

  for (int p = 1; p <= 3; p++) {
    const int gn = 1023 + p;
    if (tid < 64) s_in[tid] = s_pz[p-1][tid];
    __syncthreads();
    mamba_token(tid, b, gn, s_in, xz0, hbuf0, Win0, Wcv0, bcv0, Wxp0, Wdt0, bdt0,
                Al0, Dp0, Wo0, s_xz, s_xi, s_rg, s_dt, s_B, s_C, s_dtr, s_yp, s_y, s_ssm);
    if (tid < 64) {
      float cg = s_in[tid] + s_ssm[tid];
      s_cg[tid] = cg;
      s_in[tid] = cg;
    }
    __syncthreads();
    mamba_token(tid, b, gn, s_in, xz1, hbuf1, Win1, Wcv1, bcv1, Wxp1, Wdt1, bdt1,
                Al1, Dp1, Wo1, s_xz, s_xi, s_rg, s_dt, s_B, s_C, s_dtr, s_yp, s_y, s_ssm);
    if (tid < 64) {
      float val = s_cg[tid] + s_ssm[tid];
      float sum = val;
      #pragma unroll
      for (int m = 1; m < 64; m <<= 1) sum += __shfl_xor(sum, m);
      float mean = sum * (1.f/64.f);
      float dv = val - mean;
      float vs = dv*dv;
      #pragma unroll
      for (int m = 1; m < 64; m <<= 1) vs += __shfl_xor(vs, m);
      float oln = dv * rsqrtf(vs*(1.f/64.f) + 1e-5f) * gamma[tid] + beta[tid];
      predz[(size_t)(b*4 + p)*DM + tid] = oln;
      s_pz[p][tid] = oln;
    }
    __syncthreads();
  }

  // fused x_pred = dec(predz[0..3])
  {
    int t = tid >> 6, j = tid & 63;
    float a = bd1[j];
    const float4* zz = (const float4*)&s_pz[t][0];
    #pragma unroll 4
    for (int k4 = 0; k4 < 16; k4++) {
      float4 zv = zz[k4];
      a = fmaf(zv.x, Wd1[(k4*4+0)*64 + j], a);
      a = fmaf(zv.y, Wd1[(k4*4+1)*64 + j], a);
      a = fmaf(zv.z, Wd1[(k4*4+2)*64 + j], a);
      a = fmaf(zv.w, Wd1[(k4*4+3)*64 + j], a);
    }
    s_h[t][j] = fmaxf(a, 0.f);
  }
  __syncthreads();
  if (tid < 128) {
    int t = tid >> 5, c = tid & 31;
    float a = bd2[c];
    const float4* hh = (const float4*)&s_h[t][0];
    #pragma unroll 4
    for (int k4 = 0; k4 < 16; k4++) {
      float4 hv = hh[k4];
      a = fmaf(hv.x, Wd2[(k4*4+0)*32 + c], a);
      a = fmaf(hv.y, Wd2[(k4*4+1)*32 + c], a);
      a = fmaf(hv.z, Wd2[(k4*4+2)*32 + c], a);
      a = fmaf(hv.w, Wd2[(k4*4+3)*32 + c], a);
    }
    x_pred[(size_t)(b*4 + t)*32 + c] = a;
  }
}

extern "C" void kernel_launch(void* const* d_in, const int* in_sizes, int n_in,
                              void* d_out, int out_size, void* d_ws, size_t ws_size,
                              hipStream_t stream)
{
  (void)in_sizes; (void)n_in; (void)out_size; (void)ws_size;
  const float* x     = (const float*)d_in[0];
  const float* We1   = (const float*)d_in[1];
  const float* be1   = (const float*)d_in[2];
  const float* We2   = (const float*)d_in[3];
  const float* be2   = (const float*)d_in[4];
  const float* Wd1   = (const float*)d_in[5];
  const float* bd1   = (const float*)d_in[6];
  const float* Wd2   = (const float*)d_in[7];
  const float* bd2   = (const float*)d_in[8];
  const float* Win   = (const float*)d_in[9];
  const float* Wconv = (const float*)d_in[10];
  const float* bconv = (const float*)d_in[11];
  const float* Wxp   = (const float*)d_in[12];
  const float* Wdt   = (const float*)d_in[13];
  const float* bdt   = (const float*)d_in[14];
  const float* Alog  = (const float*)d_in[15];
  const float* Dp    = (const float*)d_in[16];
  const float* Wout  = (const float*)d_in[17];
  const float* gamma = (const float*)d_in[18];
  const float* beta  = (const float*)d_in[19];

  float* o      = (float*)d_out;
  float* x_rec  = o;                 // 8*1024*32
  float* x_dyn  = o + 262144;        // 8*1024*32
  float* x_pred = o + 524288;        // 8*4*32
  float* z      = o + 525312;        // 8*1024*64
  float* zdyn   = o + 1049600;       // 8*1024*64

  float* w      = (float*)d_ws;
  float* xi0    = w;                            // 1048576
  float* resg0  = xi0   + 1048576;              // 1048576
  float2* dd0   = (float2*)(resg0 + 1048576);   // 2097152 floats
  float* Bb0    = resg0 + 1048576 + 2097152;    // 262144
  float* Cb0    = Bb0   + 262144;               // 262144
  float* xi1    = Cb0   + 262144;               // 1048576
  float* resg1  = xi1   + 1048576;              // 1048576
  float2* dd1   = (float2*)(resg1 + 1048576);   // 2097152 floats
  float* Bb1    = resg1 + 1048576 + 2097152;    // 262144
  float* Cb1    = Bb1   + 262144;               // 262144
  float* ys     = Cb1   + 262144;               // 1048576
  float2* hc    = (float2*)(ys + 1048576);      // 1048576 floats
  float* predz  = ys + 1048576 + 1048576;       // 2048
  float* xz0    = predz + 2048;                 // 1052672 (8*1028*128)
  float* xz1    = xz0   + 1052672;              // 1052672
  float* curg   = xz1   + 1052672;              // 526336 (8*1028*64)
  float* hbuf0  = curg  + 526336;               // 32768
  float* hbuf1  = hbuf0 + 32768;                // 32768

  const float* Win0 = Win,   *Win1 = Win + 64*256;
  const float* Wcv0 = Wconv, *Wcv1 = Wconv + 128*4;
  const float* bcv0 = bconv, *bcv1 = bconv + 128;
  const float* Wxp0 = Wxp,   *Wxp1 = Wxp + 128*68;
  const float* Wdt0 = Wdt,   *Wdt1 = Wdt + 4*128;
  const float* bdt0 = bdt,   *bdt1 = bdt + 128;
  const float* Al0  = Alog,  *Al1  = Alog + 128*32;
  const float* Dp0  = Dp,    *Dp1  = Dp + 128;
  const float* Wo0  = Wout,  *Wo1  = Wout + 128*64;

  // ---- fusedA: encoder + x_rec + block-0 pre ----
  encpre_kernel<<<dim3(1024), dim3(256), 0, stream>>>(x, We1, be1, We2, be2, Wd1, bd1, Wd2, bd2,
                                                      z, x_rec,
                                                      Win0, Wcv0, bcv0, Wxp0, Wdt0, bdt0,
                                                      xi0, resg0, dd0, Bb0, Cb0, xz0);
  scan1_kernel<<<dim3(4096), dim3(128), 0, stream>>>(dd0, Bb0, Al0, hc);
  scan3_kernel<<<dim3(4096), dim3(128), 0, stream>>>(dd0, Bb0, Cb0, Al0, hc, ys, hbuf0);

  // ---- fusedB: block-0 post (curg) + block-1 pre ----
  postpre_kernel<<<dim3(1024), dim3(256), 0, stream>>>(ys, xi0, resg0, Dp0, Wo0, z,
                                                       Win1, Wcv1, bcv1, Wxp1, Wdt1, bdt1,
                                                       curg,
                                                       xi1, resg1, dd1, Bb1, Cb1, xz1);
  scan1_kernel<<<dim3(4096), dim3(128), 0, stream>>>(dd1, Bb1, Al1, hc);
  scan3_kernel<<<dim3(4096), dim3(128), 0, stream>>>(dd1, Bb1, Cb1, Al1, hc, ys, hbuf1);

  // ---- post1: LN -> zdyn/predz0 + fused x_dyn decoder ----
  post_kernel<<<dim3(1024), dim3(256), 0, stream>>>(ys, xi1, resg1, Dp1, Wo1,
                                                    curg, GEXT,
                                                    zdyn, predz, gamma, beta,
                                                    Wd1, bd1, Wd2, bd2, x_dyn);

  // ---- pred passes 1..3 + x_pred decoder: ONE kernel ----
  ext_all_kernel<<<dim3(8), dim3(256), 0, stream>>>(predz, xz0, xz1, hbuf0, hbuf1,
      Win0, Wcv0, bcv0, Wxp0, Wdt0, bdt0, Al0, Dp0, Wo0,
      Win1, Wcv1, bcv1, Wxp1, Wdt1, bdt1, Al1, Dp1, Wo1,
      gamma, beta, Wd1, bd1, Wd2, bd2, x_pred);
}